// Round 1
// baseline (154.937 us; speedup 1.0000x reference)
//
#include <hip/hip_runtime.h>
#include <hip/hip_bf16.h>
#include <math.h>

#define NPIX 4096

typedef __attribute__((ext_vector_type(8))) short s8;    // 8 x bf16 (4 VGPRs)
typedef __attribute__((ext_vector_type(16))) float f16v; // 16 x f32 (32x32 acc)

static __device__ __forceinline__ unsigned packbf2(float a, float b) {
    union { __hip_bfloat162 h; unsigned u; } x;
    x.h = __float22bfloat162_rn(make_float2(a, b));
    return x.u;
}
static __device__ __forceinline__ float fexp2(float x) {
#if __has_builtin(__builtin_amdgcn_exp2f)
    return __builtin_amdgcn_exp2f(x);
#else
    return exp2f(x);
#endif
}

// Half-swap of two regs across the lane<32 / lane>=32 boundary:
//   x = {a.row0, b.row0}  (lanes<32 keep a; lanes>=32 get b's lanes 0..31)
//   y = {a.row1, b.row1}  (lanes<32 get a's lanes 32..63; lanes>=32 keep b)
static __device__ __forceinline__ void lane_swap(unsigned a, unsigned b, int lh,
                                                 unsigned &x, unsigned &y) {
#if __has_builtin(__builtin_amdgcn_permlane32_swap)
    auto r = __builtin_amdgcn_permlane32_swap((int)a, (int)b, false, false);
    x = (unsigned)r[0];
    y = (unsigned)r[1];
#else
    unsigned sa = __shfl_xor(a, 32), sb = __shfl_xor(b, 32);
    x = lh ? sb : a;
    y = lh ? b : sa;
#endif
}

// ---------------------------------------------------------------------------
// Kernel 1: prep — q,k projections (bf16) + bf16 copy of x. (unchanged)
// ---------------------------------------------------------------------------
__global__ __launch_bounds__(256) void prep_kernel(
    const float* __restrict__ x,
    const float* __restrict__ Wq, const float* __restrict__ bq,
    const float* __restrict__ Wk, const float* __restrict__ bk,
    __hip_bfloat16* __restrict__ qbf, __hip_bfloat16* __restrict__ kbf,
    __hip_bfloat16* __restrict__ xbf)
{
    __shared__ float Xp[64][65];
    int t = threadIdx.x;
    int lane = t & 63;
    int grp  = t >> 6;               // 0..3, wave-uniform
    int b  = blockIdx.x >> 6;
    int n0 = (blockIdx.x & 63) << 6;

    const float* xb = x + ((size_t)b << 18);
    __hip_bfloat16* xbb = xbf + ((size_t)b << 18);
#pragma unroll
    for (int u = 0; u < 16; ++u) {
        int c = grp + u * 4;
        float v = xb[((size_t)c << 12) + n0 + lane];
        Xp[c][lane] = v;
        xbb[((size_t)c << 12) + n0 + lane] = __float2bfloat16(v);
    }
    __syncthreads();

    int o0 = grp * 2, o1 = o0 + 1;
    float qa0 = bq[o0], qa1 = bq[o1], ka0 = bk[o0], ka1 = bk[o1];
    const float* wq0 = Wq + o0 * 64; const float* wq1 = Wq + o1 * 64;
    const float* wk0 = Wk + o0 * 64; const float* wk1 = Wk + o1 * 64;
#pragma unroll
    for (int c = 0; c < 64; ++c) {
        float xv = Xp[c][lane];
        qa0 = fmaf(wq0[c], xv, qa0);
        qa1 = fmaf(wq1[c], xv, qa1);
        ka0 = fmaf(wk0[c], xv, ka0);
        ka1 = fmaf(wk1[c], xv, ka1);
    }
    qa0 *= 1.4426950408889634f;        // fold log2(e): flash uses exp2
    qa1 *= 1.4426950408889634f;
    int pix = b * NPIX + n0 + lane;
    *(__hip_bfloat162*)(qbf + (size_t)pix * 8 + o0) =
        __float22bfloat162_rn(make_float2(qa0, qa1));
    *(__hip_bfloat162*)(kbf + (size_t)pix * 8 + o0) =
        __float22bfloat162_rn(make_float2(ka0, ka1));
}

// ---------------------------------------------------------------------------
// Kernel 2: fused flash.
// R15 changes vs prior version:
//  * Xs double-buffered 2x32KB (stride 256 shorts, XOR-swizzled 16B granules:
//    granule g at row c lives at g^(c&7)) -> ONE barrier per tile.
//  * staging lane map c=(t&7)+8w, seg=(t>>3)&7, b128 writes: conflict-free
//    under any phase grouping (old map was 4-way on every write = the
//    entire measured 6.29M conflict count: 12.0 extra cyc/write exactly).
//  * PV uses mfma_32x32x16_bf16 (half the MFMA issue cycles of 32x32x8_1k);
//    B-frag built from packed P pairs with 4 permlane32_swap.
// ---------------------------------------------------------------------------
__global__ __launch_bounds__(512, 4) void flash_fused_kernel(
    const __hip_bfloat16* __restrict__ qbf, const __hip_bfloat16* __restrict__ kbf,
    const __hip_bfloat16* __restrict__ xbf,
    const float* __restrict__ Wv, const float* __restrict__ bv,
    const float* __restrict__ x, const float* __restrict__ gamma,
    float* __restrict__ out)
{
    // main loop: Xs0 @0 (32768), Xs1 @32768 (32768)
    // epilogue (after final barrier, overlays Xs):
    //   OshA [32][68] @0 | OshB @8704 | Linv @17408 | bvs @17536 |
    //   Wvs @17792 (16384, ends 34176) | Lsh [8][32] @34176 (ends 35200)
    __shared__ __align__(16) char pool[65536];
    unsigned short* Xs0 = (unsigned short*)pool;
    unsigned short* Xs1 = (unsigned short*)(pool + 32768);

    int t = threadIdx.x;
    int w    = t >> 6;               // 0..7 = j-stripe
    int lane = t & 63;
    int l32  = lane & 31;
    int lh   = lane >> 5;

    int b  = blockIdx.x >> 7;
    int i0 = (blockIdx.x & 127) << 5;

    const s8 zero8 = {0, 0, 0, 0, 0, 0, 0, 0};

    // Q B-frag: B[k=lh*8+r -> d][n=l32 -> i=i0+l32]; lh=1 half zeroed (d<8)
    s8 qf;
    {
        s8 qv = *(const s8*)(qbf + ((size_t)(b * NPIX + i0 + l32) << 3));
        qf = (lh == 0) ? qv : zero8;
    }

    f16v acc[2];                      // acc[cm]: O[c=cm*32+row(r,lh)][i=l32]
    f16v zero16;
#pragma unroll
    for (int r = 0; r < 16; ++r) { acc[0][r] = 0.f; acc[1][r] = 0.f; zero16[r] = 0.f; }
    float lsum = 0.f;

    const __hip_bfloat16* kb = kbf + ((size_t)(b * NPIX) << 3);
    const unsigned short* xg = (const unsigned short*)xbf + ((size_t)b << 18);

    // staging: thread t -> row crow = (t&7)+8w, seg = (t>>3)&7 (64B = 4 granules)
    int crow = (t & 7) + (w << 3);
    int seg  = (t >> 3) & 7;
    int cx   = crow & 7;
    const unsigned short* xsrc = xg + ((size_t)crow << 12) + seg * 32;
    int wrow = crow * 256;            // shorts

    // PV read: row cr = cm*32+l32, granule g = 4w+2s+lh, swizzled g^(cr&7)
    int c7    = l32 & 7;
    int gbase = 4 * w + lh;
    int woff  = w * 32 + l32;         // kf source pixel within tile

    uint4 pv[4];
    s8 kfA, kfB;

    // ---- prologue: tile0 -> Xs0; tile1 -> pv; kfA=k(t0), kfB=k(t1) ----
#pragma unroll
    for (int u = 0; u < 4; ++u) pv[u] = *(const uint4*)(xsrc + u * 8);
    kfA = *(const s8*)(kb + ((size_t)(0 * 256 + woff) << 3));
    kfB = *(const s8*)(kb + ((size_t)(1 * 256 + woff) << 3));
#pragma unroll
    for (int u = 0; u < 4; ++u)
        *(uint4*)(Xs0 + wrow + ((((seg << 2) + u) ^ cx) << 3)) = pv[u];
#pragma unroll
    for (int u = 0; u < 4; ++u) pv[u] = *(const uint4*)(xsrc + 256 + u * 8);
    __syncthreads();

    auto body = [&](int jt, const unsigned short* XsC, unsigned short* XsN, s8& kf) {
        // stage-write tile jt+1 (pv) into the other buffer
        if (jt < 15) {
#pragma unroll
            for (int u = 0; u < 4; ++u)
                *(uint4*)(XsN + wrow + ((((seg << 2) + u) ^ cx) << 3)) = pv[u];
        }

        // score (register-only): S^T[j=stripe row][i=l32]
        f16v sC = __builtin_amdgcn_mfma_f32_32x32x16_bf16(kf, qf, zero16, 0, 0, 0);

        // prefetch tile jt+2 (covered by score VALU + PV below; drained at barrier)
        if (jt < 14) {
#pragma unroll
            for (int u = 0; u < 4; ++u)
                pv[u] = *(const uint4*)(xsrc + (jt + 2) * 256 + u * 8);
            kf = *(const s8*)(kb + ((size_t)((jt + 2) * 256 + woff) << 3));
        }

        float e[16];
#pragma unroll
        for (int r = 0; r < 16; ++r) e[r] = fexp2(sC[r]);
#pragma unroll
        for (int r = 0; r < 16; ++r) lsum += e[r];
        unsigned P2[8];
#pragma unroll
        for (int s = 0; s < 8; ++s) P2[s] = packbf2(e[2 * s], e[2 * s + 1]);

        // build K=16 B-frags: bf0 covers j_local 0..15, bf1 covers 16..31
        unsigned b00, b01, b02, b03, b10, b11, b12, b13;
        lane_swap(P2[0], P2[2], lh, b00, b02);
        lane_swap(P2[1], P2[3], lh, b01, b03);
        lane_swap(P2[4], P2[6], lh, b10, b12);
        lane_swap(P2[5], P2[7], lh, b11, b13);
        union { unsigned u[4]; s8 v; } bf0, bf1;
        bf0.u[0] = b00; bf0.u[1] = b01; bf0.u[2] = b02; bf0.u[3] = b03;
        bf1.u[0] = b10; bf1.u[1] = b11; bf1.u[2] = b12; bf1.u[3] = b13;

        // P·x: O[c][i] += X[c][j-stripe] · P[j][i]  (conflict-free b128 reads)
        {
            const unsigned short* xb0 = XsC + l32 * 256;
            const unsigned short* xb1 = XsC + (32 + l32) * 256;
            s8 xf;
            xf = *(const s8*)(xb0 + (((gbase + 0) ^ c7) << 3));
            acc[0] = __builtin_amdgcn_mfma_f32_32x32x16_bf16(xf, bf0.v, acc[0], 0, 0, 0);
            xf = *(const s8*)(xb0 + (((gbase + 2) ^ c7) << 3));
            acc[0] = __builtin_amdgcn_mfma_f32_32x32x16_bf16(xf, bf1.v, acc[0], 0, 0, 0);
            xf = *(const s8*)(xb1 + (((gbase + 0) ^ c7) << 3));
            acc[1] = __builtin_amdgcn_mfma_f32_32x32x16_bf16(xf, bf0.v, acc[1], 0, 0, 0);
            xf = *(const s8*)(xb1 + (((gbase + 2) ^ c7) << 3));
            acc[1] = __builtin_amdgcn_mfma_f32_32x32x16_bf16(xf, bf1.v, acc[1], 0, 0, 0);
        }

        __syncthreads();   // tile jt+1 staged; buffer jt's readers done
    };

    for (int jt = 0; jt < 16; jt += 2) {
        body(jt,     Xs0, Xs1, kfA);
        body(jt + 1, Xs1, Xs0, kfB);
    }

    // ---------------- epilogue (block-local; last body barrier fences Xs) ----
    float* OshA = (float*)pool;                  // [32 i][68]
    float* OshB = (float*)(pool + 8704);         // [32 i][68]
    float* Linv = (float*)(pool + 17408);        // [32]
    float* bvs  = (float*)(pool + 17536);        // [64]
    float* Wvs  = (float*)(pool + 17792);        // [64][64]
    float* Lsh  = (float*)(pool + 34176);        // [8][32]

    lsum += __shfl_xor(lsum, 32);                // full 32-j stripe sum per i
    if (lh == 0) Lsh[w * 32 + l32] = lsum;       // safe: after final barrier

    // 2-tree stripe reduction: waves 0-3 -> OshA, waves 4-7 -> OshB
    float* Og = (w >> 2) ? OshB : OshA;
    for (int s = 0; s < 4; ++s) {
        __syncthreads();
        if ((w & 3) == s) {
#pragma unroll
            for (int cm = 0; cm < 2; ++cm)
#pragma unroll
                for (int r = 0; r < 16; ++r) {
                    int cc = cm * 32 + (r & 3) + 8 * (r >> 2) + 4 * lh;
                    float* p = Og + l32 * 68 + cc;
                    if (s == 0) *p = acc[cm][r];
                    else        *p += acc[cm][r];
                }
        }
    }
    __syncthreads();

    // stage Linv / bv / Wv
    if (t < 32) {
        float lt = 0.f;
#pragma unroll
        for (int ww = 0; ww < 8; ++ww) lt += Lsh[ww * 32 + t];
        Linv[t] = 1.0f / lt;
    }
    if (t < 64) bvs[t] = bv[t];
    {
        const float4* wsrc = (const float4*)Wv;
        float4* wdst = (float4*)Wvs;
        wdst[t] = wsrc[t];
        wdst[t + 512] = wsrc[t + 512];
    }
    __syncthreads();

    // projection + residual: i = t&31, cg = t>>5 (0..15) -> 4 channels each
    {
        int i  = t & 31;
        int cg = t >> 5;
        float inv = Linv[i];
        float res[4] = {0.f, 0.f, 0.f, 0.f};
#pragma unroll 4
        for (int cb = 0; cb < 16; ++cb) {
            float4 oa = *(const float4*)(OshA + i * 68 + cb * 4);
            float4 ob = *(const float4*)(OshB + i * 68 + cb * 4);
            float4 o = make_float4(oa.x + ob.x, oa.y + ob.y, oa.z + ob.z, oa.w + ob.w);
#pragma unroll
            for (int k = 0; k < 4; ++k) {
                const float4 wv4 = *(const float4*)(Wvs + (cg * 4 + k) * 64 + cb * 4);
                res[k] = fmaf(wv4.x, o.x, fmaf(wv4.y, o.y, fmaf(wv4.z, o.z, fmaf(wv4.w, o.w, res[k]))));
            }
        }
        float g = gamma[0];
        const float* xr = x + ((size_t)b << 18) + i0;
        float* outp = out + ((size_t)b << 18) + i0;
#pragma unroll
        for (int k = 0; k < 4; ++k) {
            int cch = cg * 4 + k;
            float attn = fmaf(res[k], inv, bvs[cch]);
            size_t off = ((size_t)cch << 12) + i;
            outp[off] = fmaf(g, attn, xr[off]);
        }
    }
}

extern "C" void kernel_launch(void* const* d_in, const int* in_sizes, int n_in,
                              void* d_out, int out_size, void* d_ws, size_t ws_size,
                              hipStream_t stream) {
    const float* x     = (const float*)d_in[0];
    const float* Wq    = (const float*)d_in[1];
    const float* bq    = (const float*)d_in[2];
    const float* Wk    = (const float*)d_in[3];
    const float* bk    = (const float*)d_in[4];
    const float* Wv    = (const float*)d_in[5];
    const float* bv    = (const float*)d_in[6];
    const float* gamma = (const float*)d_in[7];
    float* out = (float*)d_out;

    // ws: qbf 256KB | kbf 256KB | xbf 2MB
    __hip_bfloat16* qbf = (__hip_bfloat16*)d_ws;
    __hip_bfloat16* kbf = qbf + (size_t)4 * NPIX * 8;
    __hip_bfloat16* xbf = kbf + (size_t)4 * NPIX * 8;

    prep_kernel<<<256, 256, 0, stream>>>(x, Wq, bq, Wk, bk, qbf, kbf, xbf);
    flash_fused_kernel<<<512, 512, 0, stream>>>(qbf, kbf, xbf, Wv, bv, x, gamma, out);
}

// Round 2
// 112.622 us; speedup vs baseline: 1.3757x; 1.3757x over previous
//
#include <hip/hip_runtime.h>
#include <hip/hip_bf16.h>
#include <math.h>

#define NPIX 4096

typedef __attribute__((ext_vector_type(8))) short s8;    // 8 x bf16 (4 VGPRs)
typedef __attribute__((ext_vector_type(4))) short s4;    // 4 x bf16 (2 VGPRs)
typedef __attribute__((ext_vector_type(16))) float f16v; // 16 x f32 (32x32 acc)

static __device__ __forceinline__ unsigned packbf2(float a, float b) {
    union { __hip_bfloat162 h; unsigned u; } x;
    x.h = __float22bfloat162_rn(make_float2(a, b));
    return x.u;
}
static __device__ __forceinline__ float fexp2(float x) {
#if __has_builtin(__builtin_amdgcn_exp2f)
    return __builtin_amdgcn_exp2f(x);
#else
    return exp2f(x);
#endif
}

// ---------------------------------------------------------------------------
// Kernel 1: prep — q,k projections (bf16) + bf16 copy of x. (unchanged)
// ---------------------------------------------------------------------------
__global__ __launch_bounds__(256) void prep_kernel(
    const float* __restrict__ x,
    const float* __restrict__ Wq, const float* __restrict__ bq,
    const float* __restrict__ Wk, const float* __restrict__ bk,
    __hip_bfloat16* __restrict__ qbf, __hip_bfloat16* __restrict__ kbf,
    __hip_bfloat16* __restrict__ xbf)
{
    __shared__ float Xp[64][65];
    int t = threadIdx.x;
    int lane = t & 63;
    int grp  = t >> 6;               // 0..3, wave-uniform
    int b  = blockIdx.x >> 6;
    int n0 = (blockIdx.x & 63) << 6;

    const float* xb = x + ((size_t)b << 18);
    __hip_bfloat16* xbb = xbf + ((size_t)b << 18);
#pragma unroll
    for (int u = 0; u < 16; ++u) {
        int c = grp + u * 4;
        float v = xb[((size_t)c << 12) + n0 + lane];
        Xp[c][lane] = v;
        xbb[((size_t)c << 12) + n0 + lane] = __float2bfloat16(v);
    }
    __syncthreads();

    int o0 = grp * 2, o1 = o0 + 1;
    float qa0 = bq[o0], qa1 = bq[o1], ka0 = bk[o0], ka1 = bk[o1];
    const float* wq0 = Wq + o0 * 64; const float* wq1 = Wq + o1 * 64;
    const float* wk0 = Wk + o0 * 64; const float* wk1 = Wk + o1 * 64;
#pragma unroll
    for (int c = 0; c < 64; ++c) {
        float xv = Xp[c][lane];
        qa0 = fmaf(wq0[c], xv, qa0);
        qa1 = fmaf(wq1[c], xv, qa1);
        ka0 = fmaf(wk0[c], xv, ka0);
        ka1 = fmaf(wk1[c], xv, ka1);
    }
    qa0 *= 1.4426950408889634f;        // fold log2(e): flash uses exp2
    qa1 *= 1.4426950408889634f;
    int pix = b * NPIX + n0 + lane;
    *(__hip_bfloat162*)(qbf + (size_t)pix * 8 + o0) =
        __float22bfloat162_rn(make_float2(qa0, qa1));
    *(__hip_bfloat162*)(kbf + (size_t)pix * 8 + o0) =
        __float22bfloat162_rn(make_float2(ka0, ka1));
}

// ---------------------------------------------------------------------------
// Kernel 2: fused flash — EXACT round-0 structure (41.6 us proven) with ONE
// change: the staging lane->(row,seg) map.
//   old: c = t>>3, seg = t&7  -> each 16-lane LDS write phase hit banks
//        {0,2,16,18} only = 4 dwords/bank = 16 cyc/ds_write_b64 (floor 4).
//        Measured: 6,291,456 conflicts / 524,288 writes = +12 cyc EXACTLY.
//   new: c = 8w + (t&7), seg = (t>>3)&7 -> per 16-lane phase, dword bank =
//        2*(t&7) + 16*(seg&1): 16 distinct even banks + odd partners = all
//        32 banks -> floor. Address SET per instr is identical (lane
//        permutation only): global coalescing and LDS layout unchanged.
// R1 lesson: the double-buffer/K16 rewrite spilled to scratch (46 MB
// WRITE_SIZE, MfmaUtil 4.5%) — reverted wholesale.
// ---------------------------------------------------------------------------
__global__ __launch_bounds__(512, 4) void flash_fused_kernel(
    const __hip_bfloat16* __restrict__ qbf, const __hip_bfloat16* __restrict__ kbf,
    const __hip_bfloat16* __restrict__ xbf,
    const float* __restrict__ Wv, const float* __restrict__ bv,
    const float* __restrict__ x, const float* __restrict__ gamma,
    float* __restrict__ out)
{
    // main loop: Xs [64][260] shorts @0 = 33280 B (stride 260 -> 2-bank-stride
    //            A-frag reads = free 2-way; 520 B rows keep 8B alignment)
    // epilogue:  OshA [32][68] @0 | OshB @8704 | Linv @17408 | bvs @17536 |
    //            Wvs @17792 (16384) | Lsh [8][32] @34176 (beyond Xs: no overlap)
    __shared__ __align__(16) char pool[35200];
    unsigned short* Xs = (unsigned short*)pool;

    int t = threadIdx.x;
    int w    = t >> 6;               // 0..7 = j-stripe
    int lane = t & 63;
    int l32  = lane & 31;
    int lh   = lane >> 5;

    int b  = blockIdx.x >> 7;
    int i0 = (blockIdx.x & 127) << 5;

    const s8 zero8 = {0, 0, 0, 0, 0, 0, 0, 0};

    // Q B-frag: B[k=lh*8+r -> d][n=l32 -> i=i0+l32]; lh=1 half zeroed (d<8)
    s8 qf;
    {
        s8 qv = *(const s8*)(qbf + ((size_t)(b * NPIX + i0 + l32) << 3));
        qf = (lh == 0) ? qv : zero8;
    }

    f16v acc[2];                      // acc[cm]: O[c=cm*32+row(r,lh)][i=l32]
    f16v zero16;
#pragma unroll
    for (int r = 0; r < 16; ++r) { acc[0][r] = 0.f; acc[1][r] = 0.f; zero16[r] = 0.f; }
    float lsum = 0.f;

    const __hip_bfloat16* kb = kbf + ((size_t)(b * NPIX) << 3);
    const unsigned short* xg = (const unsigned short*)xbf + ((size_t)b << 18);

    // staging: thread t -> row c = 8w + (t&7), seg = (t>>3)&7 (32 shorts = 64 B)
    // (conflict-free phase-bank spread; address set identical to old map)
    int c = (w << 3) + (t & 7), seg = (t >> 3) & 7;
    const unsigned short* xsrc = xg + ((size_t)c << 12) + seg * 32;
    int xdst = c * 260 + seg * 32;    // shorts

    // preload tile 0
    uint2 pv[8];
    s8 kf;
    {
        const unsigned short* p = xsrc;
#pragma unroll
        for (int u = 0; u < 8; ++u) pv[u] = *(const uint2*)(p + u * 4);
        kf = *(const s8*)(kb + ((size_t)(w * 32 + l32) << 3));
    }

    for (int jt = 0; jt < 16; ++jt) {
        __syncthreads();   // A: previous tile's P·x readers done with Xs

        // stage-write from prefetched regs (8 x uint2, 8B-aligned)
        {
            unsigned short* dstp = Xs + xdst;
#pragma unroll
            for (int u = 0; u < 8; ++u) *(uint2*)(dstp + u * 4) = pv[u];
        }

        // score (no Xs dependency): S^T[j=stripe row][i=l32]
        f16v sC = __builtin_amdgcn_mfma_f32_32x32x16_bf16(kf, qf, zero16, 0, 0, 0);
        float e[16];
#pragma unroll
        for (int r = 0; r < 16; ++r) e[r] = fexp2(sC[r]);
#pragma unroll
        for (int r = 0; r < 16; ++r) lsum += e[r];
        unsigned P2[8];
#pragma unroll
        for (int s = 0; s < 8; ++s) P2[s] = packbf2(e[2 * s], e[2 * s + 1]);

        __syncthreads();   // B: Xs ready (lgkm-only drain for this write set)

        // prefetch next tile (wraps; in flight under P·x)
        {
            int jn = ((jt + 1) & 15) << 8;
            const unsigned short* p = xsrc + jn;
#pragma unroll
            for (int u = 0; u < 8; ++u) pv[u] = *(const uint2*)(p + u * 4);
            kf = *(const s8*)(kb + ((size_t)(jn + w * 32 + l32) << 3));
        }

        // P·x: O[c][i] += X[c][j-stripe] · P[j][i]
#if __has_builtin(__builtin_amdgcn_mfma_f32_32x32x8bf16_1k)
#pragma unroll
        for (int cm = 0; cm < 2; ++cm) {
            const unsigned short* xrow = Xs + (cm * 32 + l32) * 260 + w * 32 + lh * 4;
#pragma unroll
            for (int q = 0; q < 4; ++q) {
                s4 xf = *(const s4*)(xrow + q * 8);
                union { uint2 u; s4 v; } pu;
                pu.u.x = P2[2 * q]; pu.u.y = P2[2 * q + 1];
                acc[cm] = __builtin_amdgcn_mfma_f32_32x32x8bf16_1k(xf, pu.v, acc[cm], 0, 0, 0);
            }
        }
#else
        {
            unsigned X0 = __shfl_xor(P2[0], 32), X1 = __shfl_xor(P2[1], 32);
            unsigned X2 = __shfl_xor(P2[2], 32), X3 = __shfl_xor(P2[3], 32);
            unsigned X4 = __shfl_xor(P2[4], 32), X5 = __shfl_xor(P2[5], 32);
            unsigned X6 = __shfl_xor(P2[6], 32), X7 = __shfl_xor(P2[7], 32);
            union { uint4 u[2]; s8 v[2]; } bf;
            bf.u[0].x = lh ? X2 : P2[0]; bf.u[0].y = lh ? X3 : P2[1];
            bf.u[0].z = lh ? P2[2] : X0; bf.u[0].w = lh ? P2[3] : X1;
            bf.u[1].x = lh ? X6 : P2[4]; bf.u[1].y = lh ? X7 : P2[5];
            bf.u[1].z = lh ? P2[6] : X4; bf.u[1].w = lh ? P2[7] : X5;
#pragma unroll
            for (int cm = 0; cm < 2; ++cm) {
                const unsigned short* xrow = Xs + (cm * 32 + l32) * 260 + w * 32 + lh * 8;
#pragma unroll
                for (int q = 0; q < 2; ++q) {
                    union { uint2 u[2]; s8 v; } xu;
                    xu.u[0] = *(const uint2*)(xrow + q * 16);
                    xu.u[1] = *(const uint2*)(xrow + q * 16 + 4);
                    acc[cm] = __builtin_amdgcn_mfma_f32_32x32x16_bf16(xu.v, bf.v[q], acc[cm], 0, 0, 0);
                }
            }
        }
#endif
    }

    // ---------------- epilogue (block-local, no fences) ----------------
    float* OshA = (float*)pool;                  // [32 i][68]
    float* OshB = (float*)(pool + 8704);         // [32 i][68]
    float* Linv = (float*)(pool + 17408);        // [32]
    float* bvs  = (float*)(pool + 17536);        // [64]
    float* Wvs  = (float*)(pool + 17792);        // [64][64]
    float* Lsh  = (float*)(pool + 34176);        // [8][32] (no Xs overlap)

    lsum += __shfl_xor(lsum, 32);                // full 32-j stripe sum per i
    if (lh == 0) Lsh[w * 32 + l32] = lsum;       // region disjoint from Xs

    // 2-tree stripe reduction: waves 0-3 -> OshA, waves 4-7 -> OshB
    float* Og = (w >> 2) ? OshB : OshA;
    for (int s = 0; s < 4; ++s) {
        __syncthreads();
        if ((w & 3) == s) {
#pragma unroll
            for (int cm = 0; cm < 2; ++cm)
#pragma unroll
                for (int r = 0; r < 16; ++r) {
                    int cc = cm * 32 + (r & 3) + 8 * (r >> 2) + 4 * lh;
                    float* p = Og + l32 * 68 + cc;
                    if (s == 0) *p = acc[cm][r];
                    else        *p += acc[cm][r];
                }
        }
    }
    __syncthreads();

    // stage Linv / bv / Wv (Wvs region beyond OshB, before Lsh)
    if (t < 32) {
        float lt = 0.f;
#pragma unroll
        for (int ww = 0; ww < 8; ++ww) lt += Lsh[ww * 32 + t];
        Linv[t] = 1.0f / lt;
    }
    if (t < 64) bvs[t] = bv[t];
    {
        const float4* wsrc = (const float4*)Wv;
        float4* wdst = (float4*)Wvs;
        wdst[t] = wsrc[t];
        wdst[t + 512] = wsrc[t + 512];
    }
    __syncthreads();

    // projection + residual: i = t&31, cg = t>>5 (0..15) -> 4 channels each
    {
        int i  = t & 31;
        int cg = t >> 5;
        float inv = Linv[i];
        float res[4] = {0.f, 0.f, 0.f, 0.f};
#pragma unroll 4
        for (int cb = 0; cb < 16; ++cb) {
            float4 oa = *(const float4*)(OshA + i * 68 + cb * 4);
            float4 ob = *(const float4*)(OshB + i * 68 + cb * 4);
            float4 o = make_float4(oa.x + ob.x, oa.y + ob.y, oa.z + ob.z, oa.w + ob.w);
#pragma unroll
            for (int k = 0; k < 4; ++k) {
                const float4 wv4 = *(const float4*)(Wvs + (cg * 4 + k) * 64 + cb * 4);
                res[k] = fmaf(wv4.x, o.x, fmaf(wv4.y, o.y, fmaf(wv4.z, o.z, fmaf(wv4.w, o.w, res[k]))));
            }
        }
        float g = gamma[0];
        const float* xr = x + ((size_t)b << 18) + i0;
        float* outp = out + ((size_t)b << 18) + i0;
#pragma unroll
        for (int k = 0; k < 4; ++k) {
            int cch = cg * 4 + k;
            float attn = fmaf(res[k], inv, bvs[cch]);
            size_t off = ((size_t)cch << 12) + i;
            outp[off] = fmaf(g, attn, xr[off]);
        }
    }
}

extern "C" void kernel_launch(void* const* d_in, const int* in_sizes, int n_in,
                              void* d_out, int out_size, void* d_ws, size_t ws_size,
                              hipStream_t stream) {
    const float* x     = (const float*)d_in[0];
    const float* Wq    = (const float*)d_in[1];
    const float* bq    = (const float*)d_in[2];
    const float* Wk    = (const float*)d_in[3];
    const float* bk    = (const float*)d_in[4];
    const float* Wv    = (const float*)d_in[5];
    const float* bv    = (const float*)d_in[6];
    const float* gamma = (const float*)d_in[7];
    float* out = (float*)d_out;

    // ws: qbf 256KB | kbf 256KB | xbf 2MB
    __hip_bfloat16* qbf = (__hip_bfloat16*)d_ws;
    __hip_bfloat16* kbf = qbf + (size_t)4 * NPIX * 8;
    __hip_bfloat16* xbf = kbf + (size_t)4 * NPIX * 8;

    prep_kernel<<<256, 256, 0, stream>>>(x, Wq, bq, Wk, bk, qbf, kbf, xbf);
    flash_fused_kernel<<<512, 512, 0, stream>>>(qbf, kbf, xbf, Wv, bv, x, gamma, out);
}